// Round 16
// baseline (235.440 us; speedup 1.0000x reference)
//
#include <hip/hip_runtime.h>
#include <hip/hip_bf16.h>
#include <cstdint>
#include <cstddef>

// Problem constants
#define NB 8
#define NP 2048
#define NK 20
#define BN 16384      // NB*NP

typedef _Float16 half8 __attribute__((ext_vector_type(8)));
typedef _Float16 half4v __attribute__((ext_vector_type(4)));
typedef float f32x4 __attribute__((ext_vector_type(4)));

__device__ __forceinline__ void gload_lds16(const void* g, void* l) {
  __builtin_amdgcn_global_load_lds(
      (const __attribute__((address_space(1))) unsigned int*)g,
      (__attribute__((address_space(3))) unsigned int*)l, 16, 0, 0);
}

// ---------------- workspace layout (bytes) ----------------
static constexpr size_t OFF_IDX   = 0;                                // int[BN*20]
static constexpr size_t OFF_XT    = OFF_IDX + (size_t)BN*NK*4;        // f32[BN*3]
static constexpr size_t OFF_XCATH = OFF_XT + (size_t)BN*3*4;          // f16[BN*512]
static constexpr size_t OFF_WT1   = OFF_XCATH + (size_t)BN*512*2;
static constexpr size_t OFF_WD1   = OFF_WT1 + 3*64*4;
static constexpr size_t OFF_BC2   = OFF_WD1 + 3*64*4;                 // f16[64*128]  [W0|W1-W0]
static constexpr size_t OFF_BC3   = OFF_BC2 + (size_t)64*128*2;       // f16[64*256]
static constexpr size_t OFF_BC4   = OFF_BC3 + (size_t)64*256*2;       // f16[128*512]
static constexpr size_t OFF_B5    = OFF_BC4 + (size_t)128*512*2;      // f16[512*1024]
static constexpr size_t OFF_YH    = OFF_B5 + (size_t)512*1024*2;      // f16[BN*512]  [y|sbase]
static constexpr size_t OFF_HSEL  = OFF_YH + (size_t)BN*512*2;        // f16[BN*256] (sign-selected)
static constexpr size_t OFF_SPARE = OFF_HSEL + (size_t)BN*256*4;      // (H5 overlay tail)
static constexpr size_t OFF_H5    = OFF_HSEL;                         // f16[BN*1024] overlay (32MB)
static constexpr size_t OFF_PART  = OFF_SPARE + (size_t)BN*256*4;     // 8 MB partials
static constexpr size_t OFF_PMEAN = OFF_PART + (size_t)8*1024*1024;   // f32[8*8*1024]
static constexpr size_t OFF_SS    = OFF_PMEAN + (size_t)8*8*1024*4;   // f32[2*1024]
static constexpr size_t OFF_Z     = OFF_SS + 2*1024*4;                // f32[8*2048]
static constexpr size_t OFF_Z1P   = OFF_Z + (size_t)NB*2048*4;
static constexpr size_t OFF_Z2P   = OFF_Z1P + NB*512*4;
static constexpr size_t OFF_L1H   = OFF_Z2P + (size_t)NB*256*4;       // f16[512*2048]
// total ~81 MB

// ---------------- prep helpers ----------------
__device__ __forceinline__ void prep_b_dev(const float* __restrict__ W,
                                           _Float16* __restrict__ Bp, int t,
                                           int K2, int lgO, int lgRS) {
  int O = 1 << lgO;
  int o = t & (O - 1), k = t >> lgO;
  float v = W[((size_t)o << lgRS) + k];
  int ch = k >> 6, ks = (k >> 5) & 1, kg = (k >> 3) & 3, e = k & 7;
  int sl = o >> 4, ol = o & 15;
  size_t flat = (((size_t)(ch * 2 + ks) * (O >> 4) + sl) * 64 + (kg * 16 + ol)) * 8 + e;
  Bp[flat] = (_Float16)v;
}

__device__ __forceinline__ void prep_bc_dev(const float* __restrict__ W,
                                            _Float16* __restrict__ Bp, int t,
                                            int C, int lgO2, int lgRS) {
  int O2 = 1 << lgO2, O = O2 >> 1;
  int o2 = t & (O2 - 1), k = t >> lgO2;
  float v;
  if (o2 < O) v = W[((size_t)o2 << lgRS) + k];
  else {
    int o = o2 - O;
    v = W[((size_t)o << lgRS) + C + k] - W[((size_t)o << lgRS) + k];
  }
  int ch = k >> 6, ks = (k >> 5) & 1, kg = (k >> 3) & 3, e = k & 7;
  int sl = o2 >> 4, ol = o2 & 15;
  size_t flat = (((size_t)(ch * 2 + ks) * (O2 >> 4) + sl) * 64 + (kg * 16 + ol)) * 8 + e;
  Bp[flat] = (_Float16)v;
}

// ---------------- top-k helpers (exact jax.lax.top_k semantics) ----------------
__device__ __forceinline__ unsigned fmap(float x) {
  unsigned b = __float_as_uint(x);
  return b ^ (unsigned)(((int)b >> 31) | 0x80000000);
}

#define INS3U(u, gi, m1, i1, m2, i2, m3, i3)             \
  {                                                      \
    bool c1 = (u) > m1;                                  \
    unsigned t_ = c1 ? m1 : (u); int ti_ = c1 ? i1 : (gi);\
    m1 = c1 ? (u) : m1;          i1 = c1 ? (gi) : i1;    \
    bool c2 = t_ > m2;                                   \
    unsigned t2_ = c2 ? m2 : t_; int t2i_ = c2 ? i2 : ti_;\
    m2 = c2 ? t_ : m2;           i2 = c2 ? ti_ : i2;     \
    bool c3 = t2_ > m3;                                  \
    m3 = c3 ? t2_ : m3;          i3 = c3 ? t2i_ : i3;    \
  }

#define SCAN3U(uv, m1, i1, m2, i2, m3, i3)                             \
  _Pragma("unroll")                                                    \
  for (int r = 0; r < 8; ++r) {                                        \
    _Pragma("unroll")                                                  \
    for (int e = 0; e < 4; ++e) {                                      \
      unsigned val = uv[r][e];                                         \
      int gi = r * 256 + l * 4 + e;                                    \
      INS3U(val, gi, m1, i1, m2, i2, m3, i3)                           \
    }                                                                  \
  }

#define SCAN3UM(uv, dead, m1, i1, m2, i2, m3, i3)                      \
  _Pragma("unroll")                                                    \
  for (int r = 0; r < 8; ++r) {                                        \
    _Pragma("unroll")                                                  \
    for (int e = 0; e < 4; ++e) {                                      \
      int el = r * 4 + e;                                              \
      unsigned val = ((dead >> el) & 1u) ? 0u : uv[r][e];              \
      int gi = r * 256 + l * 4 + e;                                    \
      INS3U(val, gi, m1, i1, m2, i2, m3, i3)                           \
    }                                                                  \
  }

template <int CTRL>
__device__ __forceinline__ void dpp_pair_max(unsigned& hi, unsigned& lo) {
  unsigned h2 = (unsigned)__builtin_amdgcn_update_dpp((int)hi, (int)hi, CTRL, 0xF, 0xF, false);
  unsigned l2 = (unsigned)__builtin_amdgcn_update_dpp((int)lo, (int)lo, CTRL, 0xF, 0xF, false);
  bool take = (h2 > hi) || (h2 == hi && l2 > lo);
  hi = take ? h2 : hi;
  lo = take ? l2 : lo;
}

__device__ __forceinline__ void topk_row(const float* __restrict__ g,
                                         int* __restrict__ out, int l) {
  unsigned uv[8][4];
#pragma unroll
  for (int r = 0; r < 8; ++r) {
    float4 v = *(const float4*)&g[r * 256 + l * 4];
    uv[r][0] = fmap(v.x); uv[r][1] = fmap(v.y);
    uv[r][2] = fmap(v.z); uv[r][3] = fmap(v.w);
  }
  unsigned int dead = 0;
  unsigned m1 = 0, m2 = 0, m3 = 0;
  int i1 = 0, i2 = 0, i3 = 0;
  SCAN3U(uv, m1, i1, m2, i2, m3, i3)
  for (int it = 0; it < NK; ++it) {
    unsigned hi = m1, lo = ~(unsigned)i1;
    dpp_pair_max<0x111>(hi, lo);
    dpp_pair_max<0x112>(hi, lo);
    dpp_pair_max<0x114>(hi, lo);
    dpp_pair_max<0x118>(hi, lo);
    dpp_pair_max<0x142>(hi, lo);
    dpp_pair_max<0x143>(hi, lo);
    int best_i = ~(unsigned)__builtin_amdgcn_readlane((int)lo, 63);
    if (l == 0) out[it] = best_i;
    if (((best_i >> 2) & 63) == l) {       // winner lane only (index encodes lane)
      dead |= 1u << (((best_i >> 8) << 2) | (best_i & 3));
      m1 = m2; i1 = i2; m2 = m3; i2 = i3; m3 = 0; i3 = 0;
      if (m1 == 0) { SCAN3UM(uv, dead, m1, i1, m2, i2, m3, i3) }
    }
  }
}

// ---------------- fused topk + prep (topk first: longest pole issues early) ----------------
static constexpr int NTOPK = BN / 4;           // 4096 topk blocks (first)
static constexpr int PB_TR  = 0;               // 192 blocks: transpose x
static constexpr int PB_W1  = PB_TR + 192;     // 1 block
static constexpr int PB_BC2 = PB_W1 + 1;       // 32
static constexpr int PB_BC3 = PB_BC2 + 32;     // 64
static constexpr int PB_BC4 = PB_BC3 + 64;     // 256
static constexpr int PB_B5  = PB_BC4 + 256;    // 2048
static constexpr int PB_L1H = PB_B5 + 2048;    // 4096 (512*2048 / 256)
static constexpr int PB_END = PB_L1H + 4096;   // 6689

__global__ __launch_bounds__(256) void k_prep_topk(
    const float* __restrict__ x, float* __restrict__ xt,
    const float* __restrict__ W1, float* __restrict__ wt1, float* __restrict__ wd1,
    const float* __restrict__ W2, _Float16* __restrict__ bc2,
    const float* __restrict__ W3, _Float16* __restrict__ bc3,
    const float* __restrict__ W4, _Float16* __restrict__ bc4,
    const float* __restrict__ W5, _Float16* __restrict__ b5,
    const float* __restrict__ L1, _Float16* __restrict__ l1h,
    const float* __restrict__ geod, int* __restrict__ idx) {
  int blk = blockIdx.x, tid = threadIdx.x;
  if (blk < NTOPK) {                       // topk: 4 rows per block (1/wave)
    int wv = tid >> 6, l = tid & 63;
    int row = blk * 4 + wv;
    topk_row(geod + (size_t)row * NP, idx + (size_t)row * NK, l);
    return;
  }
  blk -= NTOPK;
  if (blk < PB_W1) {                       // transpose x (B,3,N)->(B,N,3)
    int t = blk * 256 + tid;
    int n = t & (NP - 1);
    int c = (t / NP) % 3;
    int b = t / (3 * NP);
    xt[(size_t)(b * NP + n) * 3 + c] = x[t];
  } else if (blk < PB_BC2) {               // layer-1 weights
    int t = tid;
    if (t < 192) {
      int o = t & 63, c = t >> 6;
      float w0 = W1[o * 6 + c];
      float w1 = W1[o * 6 + 3 + c];
      wt1[c * 64 + o] = w0;
      wd1[c * 64 + o] = w1 - w0;
    }
  } else if (blk < PB_BC3) prep_bc_dev(W2, bc2, (blk - PB_BC2) * 256 + tid, 64, 7, 7);
  else if (blk < PB_BC4)   prep_bc_dev(W3, bc3, (blk - PB_BC3) * 256 + tid, 64, 8, 7);
  else if (blk < PB_B5)    prep_bc_dev(W4, bc4, (blk - PB_BC4) * 256 + tid, 128, 9, 8);
  else if (blk < PB_L1H)   prep_b_dev(W5, b5,   (blk - PB_B5) * 256 + tid, 512, 10, 9);
  else {                                   // L1 -> fp16
    int t = (blk - PB_L1H) * 256 + tid;
    l1h[t] = (_Float16)L1[t];
  }
}

// ---------------- layer-1 EdgeConv (C=3): whole-cloud-in-LDS ----------------
__global__ __launch_bounds__(256) void k_edge1(
    const float* __restrict__ xt, const int* __restrict__ idx,
    const float* __restrict__ wt1, const float* __restrict__ wd1,
    const float* __restrict__ gamma,
    _Float16* __restrict__ hsel, float* __restrict__ part) {
  __shared__ float xl[NP * 3];          // 24KB
  __shared__ int lidx[32 * NK];
  __shared__ float red[256];
  int tid = threadIdx.x;
  int b = blockIdx.x >> 6;
  int grp = blockIdx.x & 63;
  int p0 = grp * 32;
  for (int u = tid; u < NP * 3; u += 256) xl[u] = xt[(size_t)b * NP * 3 + u];
  for (int u = tid; u < 32 * NK; u += 256) lidx[u] = idx[((size_t)b * NP + p0) * NK + u];
  __syncthreads();
  int o = tid & 63;
  int pb = tid >> 6;
  float w0 = wt1[o], w1 = wt1[64 + o], w2 = wt1[128 + o];
  float d0 = wd1[o], d1 = wd1[64 + o], d2 = wd1[128 + o];
  bool pos = gamma[o] >= 0.f;
  float ps = 0.f, ps2 = 0.f;
#pragma unroll
  for (int i = 0; i < 8; ++i) {
    int pp = pb * 8 + i;
    int p = p0 + pp;
    float base = xl[p * 3] * d0 + xl[p * 3 + 1] * d1 + xl[p * 3 + 2] * d2;
    float mx = -3.4e38f, mn = 3.4e38f;
    for (int j = 0; j < NK; ++j) {
      int nb = lidx[pp * NK + j];
      float h = base + xl[nb * 3] * w0 + xl[nb * 3 + 1] * w1 + xl[nb * 3 + 2] * w2;
      mx = fmaxf(mx, h); mn = fminf(mn, h);
      ps += h; ps2 += h * h;
    }
    size_t P = (size_t)b * NP + p;
    hsel[P * 64 + o] = (_Float16)(pos ? mx : mn);
  }
  red[tid] = ps;
  __syncthreads();
  if (tid < 64) {
    float a = red[tid] + red[64 + tid] + red[128 + tid] + red[192 + tid];
    part[(size_t)blockIdx.x * 64 + tid] = a;
  }
  __syncthreads();
  red[tid] = ps2;
  __syncthreads();
  if (tid < 64) {
    float a = red[tid] + red[64 + tid] + red[128 + tid] + red[192 + tid];
    part[((size_t)gridDim.x + blockIdx.x) * 64 + tid] = a;
  }
}

// ---------------- dense per-point GEMM: yH[p] = x[p]·[W0 | W1-W0] (fp16 out) ----------------
template <int C, int O2, int NSPLIT>
__global__ __launch_bounds__(256) void k_dense_mfma(
    const _Float16* __restrict__ xh, int in_off,
    const _Float16* __restrict__ Bp, _Float16* __restrict__ yH) {
  constexpr int NCH = C / 64;
  constexpr int NO = O2 / NSPLIT;
  constexpr int NSLO = NO / 16;
  constexpr int NS = NSLO / 2;
  constexpr int PAIRS = 2 * NSLO;
  __shared__ __align__(16) _Float16 ldsA[64 * 64];
  __shared__ __align__(16) _Float16 ldsB[PAIRS * 512];
  int tid = threadIdx.x, wv = tid >> 6, l = tid & 63;
  int mblk = blockIdx.x, nid = 0;
  if (NSPLIT > 1) { nid = mblk >> 8; mblk &= 255; }
  int m0 = mblk * 64;
  int n_base = nid * NO;
  int mg = wv & 1, ng = wv >> 1;
  f32x4 acc[2][NS];
#pragma unroll
  for (int m = 0; m < 2; ++m)
#pragma unroll
    for (int s = 0; s < NS; ++s)
#pragma unroll
      for (int r = 0; r < 4; ++r) acc[m][s][r] = 0.f;

  for (int ch = 0; ch < NCH; ++ch) {
#pragma unroll
    for (int it = 0; it < 2; ++it) {
      int r0 = wv * 16 + it * 8;
      int R = r0 + (l >> 3);
      int q = (l & 7) ^ (l >> 3);
      gload_lds16(xh + (size_t)(m0 + R) * 512 + in_off + ch * 64 + q * 8, ldsA + r0 * 64);
    }
    for (int u = wv; u < PAIRS; u += 4) {
      int ks = u / NSLO, sloc = u - ks * NSLO;
      gload_lds16(Bp + ((size_t)((ch * 2 + ks) * (O2 / 16) + (n_base >> 4) + sloc) * 64 + l) * 8,
                  ldsB + u * 512);
    }
    __syncthreads();
#pragma unroll
    for (int ks = 0; ks < 2; ++ks) {
      half8 b[NS];
#pragma unroll
      for (int s = 0; s < NS; ++s)
        b[s] = *(const half8*)(ldsB + (ks * NSLO + ng * NS + s) * 512 + l * 8);
#pragma unroll
      for (int mt = 0; mt < 2; ++mt) {
        int row = mg * 32 + mt * 16 + (l & 15);
        int slot = (ks * 4 + (l >> 4)) ^ (row & 7);
        half8 a = *(const half8*)(ldsA + row * 64 + slot * 8);
#pragma unroll
        for (int s = 0; s < NS; ++s)
          acc[mt][s] = __builtin_amdgcn_mfma_f32_16x16x32_f16(a, b[s], acc[mt][s], 0, 0, 0);
      }
    }
    __syncthreads();
  }
  int g = l >> 4;
#pragma unroll
  for (int s = 0; s < NS; ++s) {
    int col = n_base + ng * (NS * 16) + s * 16 + (l & 15);
#pragma unroll
    for (int mt = 0; mt < 2; ++mt)
#pragma unroll
      for (int r = 0; r < 4; ++r) {
        int row = m0 + mg * 32 + mt * 16 + 4 * g + r;
        yH[(size_t)row * O2 + col] = (_Float16)acc[mt][s][r];
      }
  }
}

// ---------------- gather pass: 8 cols/thread (half8 16B loads) ----------------
template <int O>
__global__ __launch_bounds__(256) void k_gather(
    const _Float16* __restrict__ yH, const int* __restrict__ idx,
    const float* __restrict__ gamma,
    _Float16* __restrict__ hsel, float* __restrict__ part) {
  constexpr int O2 = 2 * O;
  constexpr int CG = O / 8;          // 16B col groups
  constexpr int PPB = 256 / CG;      // points per block
  __shared__ int lidx[PPB * NK];
  __shared__ float redS[256 * 8], redQ[256 * 8];
  int tid = threadIdx.x;
  int p0 = blockIdx.x * PPB;
  int bbase = p0 & ~(NP - 1);
  for (int u = tid; u < PPB * NK; u += 256) lidx[u] = idx[(size_t)p0 * NK + u];
  __syncthreads();
  int pp = tid / CG, g = tid - pp * CG;
  int p = p0 + pp;
  half8 sb8 = *(const half8*)&yH[(size_t)p * O2 + O + g * 8];
  float sb[8], gv[8];
  float4 gv0 = *(const float4*)&gamma[g * 8];
  float4 gv1 = *(const float4*)&gamma[g * 8 + 4];
  gv[0] = gv0.x; gv[1] = gv0.y; gv[2] = gv0.z; gv[3] = gv0.w;
  gv[4] = gv1.x; gv[5] = gv1.y; gv[6] = gv1.z; gv[7] = gv1.w;
#pragma unroll
  for (int e = 0; e < 8; ++e) sb[e] = (float)sb8[e];
  float mx[8], mn[8], sm[8], sq[8];
#pragma unroll
  for (int e = 0; e < 8; ++e) { mx[e] = -3.4e38f; mn[e] = 3.4e38f; sm[e] = 0.f; sq[e] = 0.f; }
#pragma unroll
  for (int j = 0; j < NK; ++j) {
    int nb = bbase + lidx[pp * NK + j];
    half8 y8 = *(const half8*)&yH[(size_t)nb * O2 + g * 8];
#pragma unroll
    for (int e = 0; e < 8; ++e) {
      float h = (float)y8[e] + sb[e];
      mx[e] = fmaxf(mx[e], h); mn[e] = fminf(mn[e], h);
      sm[e] += h; sq[e] += h * h;
    }
  }
  half8 out;
#pragma unroll
  for (int e = 0; e < 8; ++e) {
    float sel = (gv[e] >= 0.f) ? mx[e] : mn[e];
    out[e] = (_Float16)sel;
  }
  *(half8*)&hsel[(size_t)p * O + g * 8] = out;
#pragma unroll
  for (int e = 0; e < 8; ++e) { redS[tid * 8 + e] = sm[e]; redQ[tid * 8 + e] = sq[e]; }
  __syncthreads();
  if (tid < CG) {
    float a[8], q[8];
#pragma unroll
    for (int e = 0; e < 8; ++e) { a[e] = redS[tid * 8 + e]; q[e] = redQ[tid * 8 + e]; }
    for (int k = 1; k < PPB; ++k)
#pragma unroll
      for (int e = 0; e < 8; ++e) {
        a[e] += redS[(tid + k * CG) * 8 + e];
        q[e] += redQ[(tid + k * CG) * 8 + e];
      }
    *(float4*)&part[(size_t)blockIdx.x * O + tid * 8]     = make_float4(a[0], a[1], a[2], a[3]);
    *(float4*)&part[(size_t)blockIdx.x * O + tid * 8 + 4] = make_float4(a[4], a[5], a[6], a[7]);
    *(float4*)&part[((size_t)gridDim.x + blockIdx.x) * O + tid * 8]     = make_float4(q[0], q[1], q[2], q[3]);
    *(float4*)&part[((size_t)gridDim.x + blockIdx.x) * O + tid * 8 + 4] = make_float4(q[4], q[5], q[6], q[7]);
  }
}

// ---------------- conv5 MFMA: 64x256 tile. h5 = xcatH(16384x512) * B5(512x1024) ----------------
__global__ __launch_bounds__(256) void k_conv5_mfma(
    const _Float16* __restrict__ xh, const _Float16* __restrict__ Bp,
    const float* __restrict__ gamma,
    _Float16* __restrict__ h5, float* __restrict__ part) {
  __shared__ __align__(16) _Float16 ldsA[64 * 64];
  __shared__ __align__(16) _Float16 ldsB[32 * 512];
  __shared__ float ldsS[2][256], ldsQ[2][256], ldsMx[2][256], ldsMn[2][256];
  int tid = threadIdx.x, wv = tid >> 6, l = tid & 63;
  int mblk = blockIdx.x & 255, nid = blockIdx.x >> 8;
  int m0 = mblk * 64;
  int n_base = nid * 256;
  int mg = wv & 1, ng = wv >> 1;
  f32x4 acc[2][8];
#pragma unroll
  for (int m = 0; m < 2; ++m)
#pragma unroll
    for (int s = 0; s < 8; ++s)
#pragma unroll
      for (int r = 0; r < 4; ++r) acc[m][s][r] = 0.f;

  for (int ch = 0; ch < 8; ++ch) {
#pragma unroll
    for (int it = 0; it < 2; ++it) {
      int r0 = wv * 16 + it * 8;
      int R = r0 + (l >> 3);
      int q = (l & 7) ^ (l >> 3);
      gload_lds16(xh + (size_t)(m0 + R) * 512 + ch * 64 + q * 8, ldsA + r0 * 64);
    }
    for (int u = wv; u < 32; u += 4) {
      int ks = u >> 4, sloc = u & 15;
      gload_lds16(Bp + ((size_t)((ch * 2 + ks) * 64 + (n_base >> 4) + sloc) * 64 + l) * 8,
                  ldsB + u * 512);
    }
    __syncthreads();
#pragma unroll
    for (int ks = 0; ks < 2; ++ks) {
      half8 b[8];
#pragma unroll
      for (int s = 0; s < 8; ++s)
        b[s] = *(const half8*)(ldsB + (ks * 16 + ng * 8 + s) * 512 + l * 8);
#pragma unroll
      for (int mt = 0; mt < 2; ++mt) {
        int row = mg * 32 + mt * 16 + (l & 15);
        int slot = (ks * 4 + (l >> 4)) ^ (row & 7);
        half8 a = *(const half8*)(ldsA + row * 64 + slot * 8);
#pragma unroll
        for (int s = 0; s < 8; ++s)
          acc[mt][s] = __builtin_amdgcn_mfma_f32_16x16x32_f16(a, b[s], acc[mt][s], 0, 0, 0);
      }
    }
    __syncthreads();
  }
  int g = l >> 4;
#pragma unroll
  for (int s = 0; s < 8; ++s) {
    float sm = 0.f, sq = 0.f, mx = -3.4e38f, mn = 3.4e38f;
    int col = n_base + ng * 128 + s * 16 + (l & 15);
#pragma unroll
    for (int mt = 0; mt < 2; ++mt)
#pragma unroll
      for (int r = 0; r < 4; ++r) {
        float v = acc[mt][s][r];
        int row = m0 + mg * 32 + mt * 16 + 4 * g + r;
        h5[(size_t)row * 1024 + col] = (_Float16)v;
        sm += v; sq += v * v; mx = fmaxf(mx, v); mn = fminf(mn, v);
      }
    sm += __shfl_xor(sm, 16); sm += __shfl_xor(sm, 32);
    sq += __shfl_xor(sq, 16); sq += __shfl_xor(sq, 32);
    mx = fmaxf(mx, __shfl_xor(mx, 16)); mx = fmaxf(mx, __shfl_xor(mx, 32));
    mn = fminf(mn, __shfl_xor(mn, 16)); mn = fminf(mn, __shfl_xor(mn, 32));
    if (l < 16) {
      int u = ng * 128 + s * 16 + l;
      ldsS[mg][u] = sm; ldsQ[mg][u] = sq; ldsMx[mg][u] = mx; ldsMn[mg][u] = mn;
    }
  }
  __syncthreads();
  {
    int u = tid;
    int col = n_base + u;
    part[(size_t)mblk * 1024 + col] = ldsS[0][u] + ldsS[1][u];
    part[((size_t)256 + mblk) * 1024 + col] = ldsQ[0][u] + ldsQ[1][u];
    float sel = (gamma[col] >= 0.f) ? fmaxf(ldsMx[0][u], ldsMx[1][u])
                                    : fminf(ldsMn[0][u], ldsMn[1][u]);
    part[((size_t)512 + mblk) * 1024 + col] = sel;
  }
}

// reduce partials -> per-channel BN scale/shift. grid = O blocks.
__global__ __launch_bounds__(256) void k_finalize(
    const float* __restrict__ part, int G, int O, float inv_count,
    const float* __restrict__ gamma, const float* __restrict__ beta,
    float* __restrict__ ss) {
  int o = blockIdx.x;
  float s = 0.f, s2 = 0.f;
  for (int g = threadIdx.x; g < G; g += 256) {
    s  += part[(size_t)g * O + o];
    s2 += part[((size_t)G + g) * O + o];
  }
#pragma unroll
  for (int sft = 32; sft; sft >>= 1) {
    s  += __shfl_down(s, sft);
    s2 += __shfl_down(s2, sft);
  }
  __shared__ float aw[4], aw2[4];
  int w = threadIdx.x >> 6;
  if ((threadIdx.x & 63) == 0) { aw[w] = s; aw2[w] = s2; }
  __syncthreads();
  if (threadIdx.x == 0) {
    s = aw[0] + aw[1] + aw[2] + aw[3];
    s2 = aw2[0] + aw2[1] + aw2[2] + aw2[3];
    float m   = s * inv_count;
    float var = s2 * inv_count - m * m;
    float scale = gamma[o] * rsqrtf(var + 1e-5f);
    ss[o]     = scale;
    ss[O + o] = beta[o] - m * scale;
  }
}

// apply BN+lrelu to the sign-selected extremum; write fp16 into xcatH slice.
__global__ void k_edge_apply(const _Float16* __restrict__ hsel,
                             const float* __restrict__ ss, _Float16* __restrict__ xh,
                             int O, int off) {
  int t = blockIdx.x * 256 + threadIdx.x;   // over BN*O/4
  int cgn = O >> 2;
  int gq = t % cgn;
  int p = t / cgn;
  int o = gq * 4;
  float4 sc = *(const float4*)&ss[o];
  float4 sh = *(const float4*)&ss[O + o];
  half4v v4 = *(const half4v*)&hsel[(size_t)p * O + o];
  float y0 = sc.x * (float)v4[0] + sh.x; y0 = (y0 >= 0.f) ? y0 : 0.2f * y0;
  float y1 = sc.y * (float)v4[1] + sh.y; y1 = (y1 >= 0.f) ? y1 : 0.2f * y1;
  float y2 = sc.z * (float)v4[2] + sh.z; y2 = (y2 >= 0.f) ? y2 : 0.2f * y2;
  float y3 = sc.w * (float)v4[3] + sh.w; y3 = (y3 >= 0.f) ? y3 : 0.2f * y3;
  half4v out;
  out[0] = (_Float16)y0; out[1] = (_Float16)y1;
  out[2] = (_Float16)y2; out[3] = (_Float16)y3;
  *(half4v*)&xh[(size_t)p * 512 + off + o] = out;
}

// conv5 mean-pool partials: grid = 8b*8ns*4cg = 256 blocks
__global__ __launch_bounds__(256) void k_pool5a(const _Float16* __restrict__ h5,
                                                const float* __restrict__ ss,
                                                float* __restrict__ pmean) {
  int bi = blockIdx.x;
  int b = bi >> 5, ns = (bi >> 2) & 7, cg = bi & 3;
  int col = cg * 256 + threadIdx.x;
  float scale = ss[col], shift = ss[1024 + col];
  float sm = 0.f;
  for (int n = ns * 256; n < ns * 256 + 256; ++n) {
    float v = (float)h5[(size_t)(b * 2048 + n) * 1024 + col];
    float y = scale * v + shift;
    y = (y >= 0.f) ? y : 0.2f * y;
    sm += y;
  }
  pmean[(size_t)(b * 8 + ns) * 1024 + col] = sm;
}

// final pool: exact extremum via fp32 sign-selected partials, mean via pmean
__global__ __launch_bounds__(256) void k_pool5b(const float* __restrict__ part,
                                                const float* __restrict__ pmean,
                                                const float* __restrict__ ss,
                                                float* __restrict__ z) {
  int bi = blockIdx.x;
  int b = bi >> 2, cg = bi & 3;
  int col = cg * 256 + threadIdx.x;
  float scale = ss[col], shift = ss[1024 + col];
  const float* psel = part + (size_t)512 * 1024;
  bool pos = scale >= 0.f;
  float hv = pos ? -3.4e38f : 3.4e38f;
  for (int q = 0; q < 32; ++q) {
    float v = psel[(size_t)(b * 32 + q) * 1024 + col];
    hv = pos ? fmaxf(hv, v) : fminf(hv, v);
  }
  float zmax = scale * hv + shift;
  zmax = (zmax >= 0.f) ? zmax : 0.2f * zmax;
  float sm = 0.f;
  for (int ns = 0; ns < 8; ++ns) sm += pmean[(size_t)(b * 8 + ns) * 1024 + col];
  z[b * 2048 + col] = zmax;
  z[b * 2048 + 1024 + col] = sm * (1.f / 2048.f);
}

// FC L1: one wave per (b,o); fp16 weights (half8 = 16B/lane)
__global__ __launch_bounds__(64) void k_fc(const float* __restrict__ in,
                                           const _Float16* __restrict__ Wf,
                                           float* __restrict__ out, int IN, int O) {
  int blk = blockIdx.x;
  int b = blk / O, o = blk % O;
  const float4* a = (const float4*)(in + (size_t)b * IN);
  const half8* w = (const half8*)(Wf + (size_t)o * IN);
  float s = 0.f;
  for (int i = threadIdx.x; i < (IN >> 3); i += 64) {
    half8 wv = w[i];
    float4 a0 = a[2 * i], a1 = a[2 * i + 1];
    s += a0.x * (float)wv[0] + a0.y * (float)wv[1] + a0.z * (float)wv[2] + a0.w * (float)wv[3]
       + a1.x * (float)wv[4] + a1.y * (float)wv[5] + a1.z * (float)wv[6] + a1.w * (float)wv[7];
  }
#pragma unroll
  for (int sft = 32; sft; sft >>= 1) s += __shfl_down(s, sft);
  if (threadIdx.x == 0) out[(size_t)b * O + o] = s;
}

// fc2 with fused bn6: each block re-derives the tiny batch-BN (8x512) in LDS,
// then 4 waves compute 4 (b,o) dot products. grid = NB*256/4 = 512 blocks.
__global__ __launch_bounds__(256) void k_fc2bn(
    const float* __restrict__ z1p,
    const float* __restrict__ g6, const float* __restrict__ bt6,
    const float* __restrict__ L2, const float* __restrict__ bl2,
    float* __restrict__ z2p) {
  __shared__ float z1[NB * 512];
  int tid = threadIdx.x;
  for (int u = tid; u < NB * 512; u += 256) z1[u] = z1p[u];
  __syncthreads();
#pragma unroll
  for (int cc = 0; cc < 2; ++cc) {       // each thread owns 2 channels exclusively
    int c = tid + cc * 256;
    float s = 0.f, s2 = 0.f;
#pragma unroll
    for (int b = 0; b < NB; ++b) {
      float v = z1[b * 512 + c];
      s += v; s2 += v * v;
    }
    float m = s * (1.f / NB);
    float var = s2 * (1.f / NB) - m * m;
    float scale = g6[c] * rsqrtf(var + 1e-5f);
    float shift = bt6[c] - m * scale;
#pragma unroll
    for (int b = 0; b < NB; ++b) {
      float y = scale * z1[b * 512 + c] + shift;
      z1[b * 512 + c] = (y >= 0.f) ? y : 0.2f * y;
    }
  }
  __syncthreads();
  int wv = tid >> 6, l = tid & 63;
  int u = blockIdx.x * 4 + wv;           // output index over NB*256
  int b = u >> 8, o = u & 255;
  const float4* a = (const float4*)&z1[b * 512];
  const float4* w = (const float4*)(L2 + (size_t)o * 512);
  float s = 0.f;
#pragma unroll
  for (int i = l; i < 128; i += 64) {
    float4 av = a[i], wvv = w[i];
    s += av.x * wvv.x + av.y * wvv.y + av.z * wvv.z + av.w * wvv.w;
  }
#pragma unroll
  for (int sft = 32; sft; sft >>= 1) s += __shfl_down(s, sft);
  if (l == 0) z2p[u] = s + bl2[o];
}

// fc3 with fused bn7: grid = NB*40/4 = 80 blocks.
__global__ __launch_bounds__(256) void k_fc3bn(
    const float* __restrict__ z2p,
    const float* __restrict__ g7, const float* __restrict__ bt7,
    const float* __restrict__ L3, const float* __restrict__ bl3,
    float* __restrict__ out) {
  __shared__ float z2[NB * 256];
  int tid = threadIdx.x;
  for (int u = tid; u < NB * 256; u += 256) z2[u] = z2p[u];
  __syncthreads();
  {
    int c = tid;                         // one channel per thread, exclusive
    float s = 0.f, s2 = 0.f;
#pragma unroll
    for (int b = 0; b < NB; ++b) {
      float v = z2[b * 256 + c];
      s += v; s2 += v * v;
    }
    float m = s * (1.f / NB);
    float var = s2 * (1.f / NB) - m * m;
    float scale = g7[c] * rsqrtf(var + 1e-5f);
    float shift = bt7[c] - m * scale;
#pragma unroll
    for (int b = 0; b < NB; ++b) {
      float y = scale * z2[b * 256 + c] + shift;
      z2[b * 256 + c] = (y >= 0.f) ? y : 0.2f * y;
    }
  }
  __syncthreads();
  int wv = tid >> 6, l = tid & 63;
  int u = blockIdx.x * 4 + wv;           // output index over NB*40
  int b = u / 40, o = u - b * 40;
  const float4* a = (const float4*)&z2[b * 256];
  const float4* w = (const float4*)(L3 + (size_t)o * 256);
  float s = 0.f;
  {
    float4 av = a[l], wvv = w[l];        // 64 float4 = 256 elems, one per lane
    s += av.x * wvv.x + av.y * wvv.y + av.z * wvv.z + av.w * wvv.w;
  }
#pragma unroll
  for (int sft = 32; sft; sft >>= 1) s += __shfl_down(s, sft);
  if (l == 0) out[u] = s + bl3[o];
}

// ---------------- launcher ----------------
extern "C" void kernel_launch(void* const* d_in, const int* in_sizes, int n_in,
                              void* d_out, int out_size, void* d_ws, size_t ws_size,
                              hipStream_t stream) {
  (void)in_sizes; (void)n_in; (void)out_size; (void)ws_size;
  const float* x    = (const float*)d_in[0];
  const float* geod = (const float*)d_in[1];
  const float* W1   = (const float*)d_in[2];
  const float* g1   = (const float*)d_in[3];
  const float* bt1  = (const float*)d_in[4];
  const float* W2   = (const float*)d_in[5];
  const float* g2   = (const float*)d_in[6];
  const float* bt2  = (const float*)d_in[7];
  const float* W3   = (const float*)d_in[8];
  const float* g3   = (const float*)d_in[9];
  const float* bt3  = (const float*)d_in[10];
  const float* W4   = (const float*)d_in[11];
  const float* g4   = (const float*)d_in[12];
  const float* bt4  = (const float*)d_in[13];
  const float* W5   = (const float*)d_in[14];
  const float* g5   = (const float*)d_in[15];
  const float* bt5  = (const float*)d_in[16];
  const float* L1   = (const float*)d_in[17];
  const float* g6   = (const float*)d_in[18];
  const float* bt6  = (const float*)d_in[19];
  const float* L2   = (const float*)d_in[20];
  const float* bl2  = (const float*)d_in[21];
  const float* g7   = (const float*)d_in[22];
  const float* bt7  = (const float*)d_in[23];
  const float* L3   = (const float*)d_in[24];
  const float* bl3  = (const float*)d_in[25];

  char* ws = (char*)d_ws;
  int*       idx   = (int*)(ws + OFF_IDX);
  float*     xt    = (float*)(ws + OFF_XT);
  _Float16*  xcatH = (_Float16*)(ws + OFF_XCATH);
  float*     wt1   = (float*)(ws + OFF_WT1);
  float*     wd1   = (float*)(ws + OFF_WD1);
  _Float16*  bc2   = (_Float16*)(ws + OFF_BC2);
  _Float16*  bc3   = (_Float16*)(ws + OFF_BC3);
  _Float16*  bc4   = (_Float16*)(ws + OFF_BC4);
  _Float16*  b5    = (_Float16*)(ws + OFF_B5);
  _Float16*  yH    = (_Float16*)(ws + OFF_YH);
  _Float16*  hsel  = (_Float16*)(ws + OFF_HSEL);
  _Float16*  h5    = (_Float16*)(ws + OFF_H5);
  float*     part  = (float*)(ws + OFF_PART);
  float*     pmean = (float*)(ws + OFF_PMEAN);
  float*     ssb   = (float*)(ws + OFF_SS);
  float*     z     = (float*)(ws + OFF_Z);
  float*     z1p   = (float*)(ws + OFF_Z1P);
  float*     z2p   = (float*)(ws + OFF_Z2P);
  _Float16*  l1h   = (_Float16*)(ws + OFF_L1H);

  const float invE = 1.f / (float)(BN * NK);
  const float inv5 = 1.f / (float)(BN);

  // fused topk (first) + prep (independent work in one dispatch)
  k_prep_topk<<<NTOPK + PB_END, 256, 0, stream>>>(x, xt, W1, wt1, wd1,
                                                  W2, bc2, W3, bc3, W4, bc4, W5, b5,
                                                  L1, l1h, geod, idx);

  // layer 1 (C=3, fp32, whole-cloud LDS)
  k_edge1<<<512, 256, 0, stream>>>(xt, idx, wt1, wd1, g1, hsel, part);
  k_finalize<<<64, 256, 0, stream>>>(part, 512, 64, invE, g1, bt1, ssb);
  k_edge_apply<<<(BN * 64) / 1024, 256, 0, stream>>>(hsel, ssb, xcatH, 64, 0);
  // layer 2 (C=64 -> O=64): dense y|sbase GEMM + gather (8 cols/thread)
  k_dense_mfma<64, 128, 1><<<256, 256, 0, stream>>>(xcatH, 0, bc2, yH);
  k_gather<64><<<BN / 32, 256, 0, stream>>>(yH, idx, g2, hsel, part);
  k_finalize<<<64, 256, 0, stream>>>(part, BN / 32, 64, invE, g2, bt2, ssb);
  k_edge_apply<<<(BN * 64) / 1024, 256, 0, stream>>>(hsel, ssb, xcatH, 64, 64);
  // layer 3 (C=64 -> O=128)
  k_dense_mfma<64, 256, 1><<<256, 256, 0, stream>>>(xcatH, 64, bc3, yH);
  k_gather<128><<<BN / 16, 256, 0, stream>>>(yH, idx, g3, hsel, part);
  k_finalize<<<128, 256, 0, stream>>>(part, BN / 16, 128, invE, g3, bt3, ssb);
  k_edge_apply<<<(BN * 128) / 1024, 256, 0, stream>>>(hsel, ssb, xcatH, 128, 128);
  // layer 4 (C=128 -> O=256)
  k_dense_mfma<128, 512, 2><<<512, 256, 0, stream>>>(xcatH, 128, bc4, yH);
  k_gather<256><<<BN / 8, 256, 0, stream>>>(yH, idx, g4, hsel, part);
  k_finalize<<<256, 256, 0, stream>>>(part, BN / 8, 256, invE, g4, bt4, ssb);
  k_edge_apply<<<(BN * 256) / 1024, 256, 0, stream>>>(hsel, ssb, xcatH, 256, 256);

  // conv5 (16384x512 @ 512x1024), 64x256 tile (3 blocks/CU — proven config)
  k_conv5_mfma<<<1024, 256, 0, stream>>>(xcatH, b5, g5, h5, part);
  k_finalize<<<1024, 256, 0, stream>>>(part, 256, 1024, inv5, g5, bt5, ssb);
  k_pool5a<<<256, 256, 0, stream>>>(h5, ssb, pmean);
  k_pool5b<<<32, 256, 0, stream>>>(part, pmean, ssb, z);

  // FC head (multi-block; batch-BNs fused into the GEMM kernels)
  k_fc<<<NB * 512, 64, 0, stream>>>(z, l1h, z1p, 2048, 512);
  k_fc2bn<<<NB * 256 / 4, 256, 0, stream>>>(z1p, g6, bt6, L2, bl2, z2p);
  k_fc3bn<<<NB * 40 / 4, 256, 0, stream>>>(z2p, g7, bt7, L3, bl3, (float*)d_out);
}

// Round 17
// 229.675 us; speedup vs baseline: 1.0251x; 1.0251x over previous
//
#include <hip/hip_runtime.h>
#include <hip/hip_bf16.h>
#include <cstdint>
#include <cstddef>

// Problem constants
#define NB 8
#define NP 2048
#define NK 20
#define BN 16384      // NB*NP

typedef _Float16 half8 __attribute__((ext_vector_type(8)));
typedef _Float16 half4v __attribute__((ext_vector_type(4)));
typedef float f32x4 __attribute__((ext_vector_type(4)));

__device__ __forceinline__ void gload_lds16(const void* g, void* l) {
  __builtin_amdgcn_global_load_lds(
      (const __attribute__((address_space(1))) unsigned int*)g,
      (__attribute__((address_space(3))) unsigned int*)l, 16, 0, 0);
}

// ---------------- workspace layout (bytes) ----------------
static constexpr size_t OFF_IDX   = 0;                                // int[BN*20]
static constexpr size_t OFF_XT    = OFF_IDX + (size_t)BN*NK*4;        // f32[BN*3]
static constexpr size_t OFF_XCATH = OFF_XT + (size_t)BN*3*4;          // f16[BN*512]
static constexpr size_t OFF_WT1   = OFF_XCATH + (size_t)BN*512*2;
static constexpr size_t OFF_WD1   = OFF_WT1 + 3*64*4;
static constexpr size_t OFF_BC2   = OFF_WD1 + 3*64*4;                 // f16[64*128]  [W0|W1-W0]
static constexpr size_t OFF_BC3   = OFF_BC2 + (size_t)64*128*2;       // f16[64*256]
static constexpr size_t OFF_BC4   = OFF_BC3 + (size_t)64*256*2;       // f16[128*512]
static constexpr size_t OFF_B5    = OFF_BC4 + (size_t)128*512*2;      // f16[512*1024]
static constexpr size_t OFF_YH    = OFF_B5 + (size_t)512*1024*2;      // f16[BN*512]  [y|sbase]
static constexpr size_t OFF_HSEL  = OFF_YH + (size_t)BN*512*2;        // f32[BN*256] (sign-selected)
static constexpr size_t OFF_SPARE = OFF_HSEL + (size_t)BN*256*4;      // (H5 overlay tail)
static constexpr size_t OFF_H5    = OFF_HSEL;                         // f16[BN*1024] overlay (32MB)
static constexpr size_t OFF_PART  = OFF_SPARE + (size_t)BN*256*4;     // 8 MB partials
static constexpr size_t OFF_PMEAN = OFF_PART + (size_t)8*1024*1024;   // f32[8*8*1024]
static constexpr size_t OFF_SS    = OFF_PMEAN + (size_t)8*8*1024*4;   // f32[2*1024]
static constexpr size_t OFF_Z     = OFF_SS + 2*1024*4;                // f32[8*2048]
static constexpr size_t OFF_Z1P   = OFF_Z + (size_t)NB*2048*4;
static constexpr size_t OFF_Z2P   = OFF_Z1P + NB*512*4;
static constexpr size_t OFF_L1H   = OFF_Z2P + (size_t)NB*256*4;       // f16[512*2048]
// total ~81 MB

// ---------------- prep helpers ----------------
__device__ __forceinline__ void prep_b_dev(const float* __restrict__ W,
                                           _Float16* __restrict__ Bp, int t,
                                           int K2, int lgO, int lgRS) {
  int O = 1 << lgO;
  int o = t & (O - 1), k = t >> lgO;
  float v = W[((size_t)o << lgRS) + k];
  int ch = k >> 6, ks = (k >> 5) & 1, kg = (k >> 3) & 3, e = k & 7;
  int sl = o >> 4, ol = o & 15;
  size_t flat = (((size_t)(ch * 2 + ks) * (O >> 4) + sl) * 64 + (kg * 16 + ol)) * 8 + e;
  Bp[flat] = (_Float16)v;
}

__device__ __forceinline__ void prep_bc_dev(const float* __restrict__ W,
                                            _Float16* __restrict__ Bp, int t,
                                            int C, int lgO2, int lgRS) {
  int O2 = 1 << lgO2, O = O2 >> 1;
  int o2 = t & (O2 - 1), k = t >> lgO2;
  float v;
  if (o2 < O) v = W[((size_t)o2 << lgRS) + k];
  else {
    int o = o2 - O;
    v = W[((size_t)o << lgRS) + C + k] - W[((size_t)o << lgRS) + k];
  }
  int ch = k >> 6, ks = (k >> 5) & 1, kg = (k >> 3) & 3, e = k & 7;
  int sl = o2 >> 4, ol = o2 & 15;
  size_t flat = (((size_t)(ch * 2 + ks) * (O2 >> 4) + sl) * 64 + (kg * 16 + ol)) * 8 + e;
  Bp[flat] = (_Float16)v;
}

// ---------------- top-k helpers (exact jax.lax.top_k semantics) ----------------
__device__ __forceinline__ unsigned fmap(float x) {
  unsigned b = __float_as_uint(x);
  return b ^ (unsigned)(((int)b >> 31) | 0x80000000);
}

#define INS3U(u, gi, m1, i1, m2, i2, m3, i3)             \
  {                                                      \
    bool c1 = (u) > m1;                                  \
    unsigned t_ = c1 ? m1 : (u); int ti_ = c1 ? i1 : (gi);\
    m1 = c1 ? (u) : m1;          i1 = c1 ? (gi) : i1;    \
    bool c2 = t_ > m2;                                   \
    unsigned t2_ = c2 ? m2 : t_; int t2i_ = c2 ? i2 : ti_;\
    m2 = c2 ? t_ : m2;           i2 = c2 ? ti_ : i2;     \
    bool c3 = t2_ > m3;                                  \
    m3 = c3 ? t2_ : m3;          i3 = c3 ? t2i_ : i3;    \
  }

#define SCAN3U(uv, m1, i1, m2, i2, m3, i3)                             \
  _Pragma("unroll")                                                    \
  for (int r = 0; r < 8; ++r) {                                        \
    _Pragma("unroll")                                                  \
    for (int e = 0; e < 4; ++e) {                                      \
      unsigned val = uv[r][e];                                         \
      int gi = r * 256 + l * 4 + e;                                    \
      INS3U(val, gi, m1, i1, m2, i2, m3, i3)                           \
    }                                                                  \
  }

#define SCAN3UM(uv, dead, m1, i1, m2, i2, m3, i3)                      \
  _Pragma("unroll")                                                    \
  for (int r = 0; r < 8; ++r) {                                        \
    _Pragma("unroll")                                                  \
    for (int e = 0; e < 4; ++e) {                                      \
      int el = r * 4 + e;                                              \
      unsigned val = ((dead >> el) & 1u) ? 0u : uv[r][e];              \
      int gi = r * 256 + l * 4 + e;                                    \
      INS3U(val, gi, m1, i1, m2, i2, m3, i3)                           \
    }                                                                  \
  }

template <int CTRL>
__device__ __forceinline__ void dpp_pair_max(unsigned& hi, unsigned& lo) {
  unsigned h2 = (unsigned)__builtin_amdgcn_update_dpp((int)hi, (int)hi, CTRL, 0xF, 0xF, false);
  unsigned l2 = (unsigned)__builtin_amdgcn_update_dpp((int)lo, (int)lo, CTRL, 0xF, 0xF, false);
  bool take = (h2 > hi) || (h2 == hi && l2 > lo);
  hi = take ? h2 : hi;
  lo = take ? l2 : lo;
}

__device__ __forceinline__ void topk_row(const float* __restrict__ g,
                                         int* __restrict__ out, int l) {
  unsigned uv[8][4];
#pragma unroll
  for (int r = 0; r < 8; ++r) {
    float4 v = *(const float4*)&g[r * 256 + l * 4];
    uv[r][0] = fmap(v.x); uv[r][1] = fmap(v.y);
    uv[r][2] = fmap(v.z); uv[r][3] = fmap(v.w);
  }
  unsigned int dead = 0;
  unsigned m1 = 0, m2 = 0, m3 = 0;
  int i1 = 0, i2 = 0, i3 = 0;
  SCAN3U(uv, m1, i1, m2, i2, m3, i3)
  for (int it = 0; it < NK; ++it) {
    unsigned hi = m1, lo = ~(unsigned)i1;
    dpp_pair_max<0x111>(hi, lo);
    dpp_pair_max<0x112>(hi, lo);
    dpp_pair_max<0x114>(hi, lo);
    dpp_pair_max<0x118>(hi, lo);
    dpp_pair_max<0x142>(hi, lo);
    dpp_pair_max<0x143>(hi, lo);
    int best_i = ~(unsigned)__builtin_amdgcn_readlane((int)lo, 63);
    if (l == 0) out[it] = best_i;
    if (((best_i >> 2) & 63) == l) {       // winner lane only (index encodes lane)
      dead |= 1u << (((best_i >> 8) << 2) | (best_i & 3));
      m1 = m2; i1 = i2; m2 = m3; i2 = i3; m3 = 0; i3 = 0;
      if (m1 == 0) { SCAN3UM(uv, dead, m1, i1, m2, i2, m3, i3) }
    }
  }
}

// ---------------- fused topk + prep (topk first: longest pole issues early) ----------------
static constexpr int NTOPK = BN / 4;           // 4096 topk blocks (first)
static constexpr int PB_TR  = 0;               // 192 blocks: transpose x
static constexpr int PB_W1  = PB_TR + 192;     // 1 block
static constexpr int PB_BC2 = PB_W1 + 1;       // 32
static constexpr int PB_BC3 = PB_BC2 + 32;     // 64
static constexpr int PB_BC4 = PB_BC3 + 64;     // 256
static constexpr int PB_B5  = PB_BC4 + 256;    // 2048
static constexpr int PB_L1H = PB_B5 + 2048;    // 4096 (512*2048 / 256)
static constexpr int PB_END = PB_L1H + 4096;   // 6689

__global__ __launch_bounds__(256) void k_prep_topk(
    const float* __restrict__ x, float* __restrict__ xt,
    const float* __restrict__ W1, float* __restrict__ wt1, float* __restrict__ wd1,
    const float* __restrict__ W2, _Float16* __restrict__ bc2,
    const float* __restrict__ W3, _Float16* __restrict__ bc3,
    const float* __restrict__ W4, _Float16* __restrict__ bc4,
    const float* __restrict__ W5, _Float16* __restrict__ b5,
    const float* __restrict__ L1, _Float16* __restrict__ l1h,
    const float* __restrict__ geod, int* __restrict__ idx) {
  int blk = blockIdx.x, tid = threadIdx.x;
  if (blk < NTOPK) {                       // topk: 4 rows per block (1/wave)
    int wv = tid >> 6, l = tid & 63;
    int row = blk * 4 + wv;
    topk_row(geod + (size_t)row * NP, idx + (size_t)row * NK, l);
    return;
  }
  blk -= NTOPK;
  if (blk < PB_W1) {                       // transpose x (B,3,N)->(B,N,3)
    int t = blk * 256 + tid;
    int n = t & (NP - 1);
    int c = (t / NP) % 3;
    int b = t / (3 * NP);
    xt[(size_t)(b * NP + n) * 3 + c] = x[t];
  } else if (blk < PB_BC2) {               // layer-1 weights
    int t = tid;
    if (t < 192) {
      int o = t & 63, c = t >> 6;
      float w0 = W1[o * 6 + c];
      float w1 = W1[o * 6 + 3 + c];
      wt1[c * 64 + o] = w0;
      wd1[c * 64 + o] = w1 - w0;
    }
  } else if (blk < PB_BC3) prep_bc_dev(W2, bc2, (blk - PB_BC2) * 256 + tid, 64, 7, 7);
  else if (blk < PB_BC4)   prep_bc_dev(W3, bc3, (blk - PB_BC3) * 256 + tid, 64, 8, 7);
  else if (blk < PB_B5)    prep_bc_dev(W4, bc4, (blk - PB_BC4) * 256 + tid, 128, 9, 8);
  else if (blk < PB_L1H)   prep_b_dev(W5, b5,   (blk - PB_B5) * 256 + tid, 512, 10, 9);
  else {                                   // L1 -> fp16
    int t = (blk - PB_L1H) * 256 + tid;
    l1h[t] = (_Float16)L1[t];
  }
}

// ---------------- layer-1 EdgeConv (C=3): whole-cloud-in-LDS ----------------
__global__ __launch_bounds__(256) void k_edge1(
    const float* __restrict__ xt, const int* __restrict__ idx,
    const float* __restrict__ wt1, const float* __restrict__ wd1,
    const float* __restrict__ gamma,
    float* __restrict__ hsel, float* __restrict__ part) {
  __shared__ float xl[NP * 3];          // 24KB
  __shared__ int lidx[32 * NK];
  __shared__ float red[256];
  int tid = threadIdx.x;
  int b = blockIdx.x >> 6;
  int grp = blockIdx.x & 63;
  int p0 = grp * 32;
  for (int u = tid; u < NP * 3; u += 256) xl[u] = xt[(size_t)b * NP * 3 + u];
  for (int u = tid; u < 32 * NK; u += 256) lidx[u] = idx[((size_t)b * NP + p0) * NK + u];
  __syncthreads();
  int o = tid & 63;
  int pb = tid >> 6;
  float w0 = wt1[o], w1 = wt1[64 + o], w2 = wt1[128 + o];
  float d0 = wd1[o], d1 = wd1[64 + o], d2 = wd1[128 + o];
  bool pos = gamma[o] >= 0.f;
  float ps = 0.f, ps2 = 0.f;
#pragma unroll
  for (int i = 0; i < 8; ++i) {
    int pp = pb * 8 + i;
    int p = p0 + pp;
    float base = xl[p * 3] * d0 + xl[p * 3 + 1] * d1 + xl[p * 3 + 2] * d2;
    float mx = -3.4e38f, mn = 3.4e38f;
    for (int j = 0; j < NK; ++j) {
      int nb = lidx[pp * NK + j];
      float h = base + xl[nb * 3] * w0 + xl[nb * 3 + 1] * w1 + xl[nb * 3 + 2] * w2;
      mx = fmaxf(mx, h); mn = fminf(mn, h);
      ps += h; ps2 += h * h;
    }
    size_t P = (size_t)b * NP + p;
    hsel[P * 64 + o] = pos ? mx : mn;
  }
  red[tid] = ps;
  __syncthreads();
  if (tid < 64) {
    float a = red[tid] + red[64 + tid] + red[128 + tid] + red[192 + tid];
    part[(size_t)blockIdx.x * 64 + tid] = a;
  }
  __syncthreads();
  red[tid] = ps2;
  __syncthreads();
  if (tid < 64) {
    float a = red[tid] + red[64 + tid] + red[128 + tid] + red[192 + tid];
    part[((size_t)gridDim.x + blockIdx.x) * 64 + tid] = a;
  }
}

// ---------------- dense per-point GEMM: yH[p] = x[p]·[W0 | W1-W0] (fp16 out) ----------------
template <int C, int O2, int NSPLIT>
__global__ __launch_bounds__(256) void k_dense_mfma(
    const _Float16* __restrict__ xh, int in_off,
    const _Float16* __restrict__ Bp, _Float16* __restrict__ yH) {
  constexpr int NCH = C / 64;
  constexpr int NO = O2 / NSPLIT;
  constexpr int NSLO = NO / 16;
  constexpr int NS = NSLO / 2;
  constexpr int PAIRS = 2 * NSLO;
  __shared__ __align__(16) _Float16 ldsA[64 * 64];
  __shared__ __align__(16) _Float16 ldsB[PAIRS * 512];
  int tid = threadIdx.x, wv = tid >> 6, l = tid & 63;
  int mblk = blockIdx.x, nid = 0;
  if (NSPLIT > 1) { nid = mblk >> 8; mblk &= 255; }
  int m0 = mblk * 64;
  int n_base = nid * NO;
  int mg = wv & 1, ng = wv >> 1;
  f32x4 acc[2][NS];
#pragma unroll
  for (int m = 0; m < 2; ++m)
#pragma unroll
    for (int s = 0; s < NS; ++s)
#pragma unroll
      for (int r = 0; r < 4; ++r) acc[m][s][r] = 0.f;

  for (int ch = 0; ch < NCH; ++ch) {
#pragma unroll
    for (int it = 0; it < 2; ++it) {
      int r0 = wv * 16 + it * 8;
      int R = r0 + (l >> 3);
      int q = (l & 7) ^ (l >> 3);
      gload_lds16(xh + (size_t)(m0 + R) * 512 + in_off + ch * 64 + q * 8, ldsA + r0 * 64);
    }
    for (int u = wv; u < PAIRS; u += 4) {
      int ks = u / NSLO, sloc = u - ks * NSLO;
      gload_lds16(Bp + ((size_t)((ch * 2 + ks) * (O2 / 16) + (n_base >> 4) + sloc) * 64 + l) * 8,
                  ldsB + u * 512);
    }
    __syncthreads();
#pragma unroll
    for (int ks = 0; ks < 2; ++ks) {
      half8 b[NS];
#pragma unroll
      for (int s = 0; s < NS; ++s)
        b[s] = *(const half8*)(ldsB + (ks * NSLO + ng * NS + s) * 512 + l * 8);
#pragma unroll
      for (int mt = 0; mt < 2; ++mt) {
        int row = mg * 32 + mt * 16 + (l & 15);
        int slot = (ks * 4 + (l >> 4)) ^ (row & 7);
        half8 a = *(const half8*)(ldsA + row * 64 + slot * 8);
#pragma unroll
        for (int s = 0; s < NS; ++s)
          acc[mt][s] = __builtin_amdgcn_mfma_f32_16x16x32_f16(a, b[s], acc[mt][s], 0, 0, 0);
      }
    }
    __syncthreads();
  }
  int g = l >> 4;
#pragma unroll
  for (int s = 0; s < NS; ++s) {
    int col = n_base + ng * (NS * 16) + s * 16 + (l & 15);
#pragma unroll
    for (int mt = 0; mt < 2; ++mt)
#pragma unroll
      for (int r = 0; r < 4; ++r) {
        int row = m0 + mg * 32 + mt * 16 + 4 * g + r;
        yH[(size_t)row * O2 + col] = (_Float16)acc[mt][s][r];
      }
  }
}

// ---------------- gather pass: per point, sign-selected extremum + sum/sumsq ----------------
template <int O>
__global__ __launch_bounds__(256) void k_gather(
    const _Float16* __restrict__ yH, const int* __restrict__ idx,
    const float* __restrict__ gamma,
    float* __restrict__ hsel, float* __restrict__ part) {
  constexpr int O2 = 2 * O;
  constexpr int CG = O / 4;
  constexpr int PPB = 256 / CG;
  __shared__ int lidx[PPB * NK];
  __shared__ float4 redS[256], redQ[256];
  int tid = threadIdx.x;
  int p0 = blockIdx.x * PPB;
  int bbase = p0 & ~(NP - 1);
  for (int u = tid; u < PPB * NK; u += 256) lidx[u] = idx[(size_t)p0 * NK + u];
  __syncthreads();
  int pp = tid / CG, g = tid - pp * CG;
  int p = p0 + pp;
  half4v sb4 = *(const half4v*)&yH[(size_t)p * O2 + O + g * 4];
  float sb[4] = {(float)sb4[0], (float)sb4[1], (float)sb4[2], (float)sb4[3]};
  float4 gv = *(const float4*)&gamma[g * 4];
  float mx[4], mn[4], sm[4], sq[4];
#pragma unroll
  for (int e = 0; e < 4; ++e) { mx[e] = -3.4e38f; mn[e] = 3.4e38f; sm[e] = 0.f; sq[e] = 0.f; }
#pragma unroll
  for (int j = 0; j < NK; ++j) {
    int nb = bbase + lidx[pp * NK + j];
    half4v y4 = *(const half4v*)&yH[(size_t)nb * O2 + g * 4];
#pragma unroll
    for (int e = 0; e < 4; ++e) {
      float h = (float)y4[e] + sb[e];
      mx[e] = fmaxf(mx[e], h); mn[e] = fminf(mn[e], h);
      sm[e] += h; sq[e] += h * h;
    }
  }
  float s0 = (gv.x >= 0.f) ? mx[0] : mn[0];
  float s1 = (gv.y >= 0.f) ? mx[1] : mn[1];
  float s2 = (gv.z >= 0.f) ? mx[2] : mn[2];
  float s3 = (gv.w >= 0.f) ? mx[3] : mn[3];
  *(float4*)&hsel[(size_t)p * O + g * 4] = make_float4(s0, s1, s2, s3);
  redS[tid] = make_float4(sm[0], sm[1], sm[2], sm[3]);
  redQ[tid] = make_float4(sq[0], sq[1], sq[2], sq[3]);
  __syncthreads();
  if (tid < CG) {
    float4 a = redS[tid], q = redQ[tid];
    for (int k = 1; k < PPB; ++k) {
      float4 b = redS[tid + k * CG], c = redQ[tid + k * CG];
      a.x += b.x; a.y += b.y; a.z += b.z; a.w += b.w;
      q.x += c.x; q.y += c.y; q.z += c.z; q.w += c.w;
    }
    *(float4*)&part[(size_t)blockIdx.x * O + tid * 4] = a;
    *(float4*)&part[((size_t)gridDim.x + blockIdx.x) * O + tid * 4] = q;
  }
}

// ---------------- conv5 MFMA: 64x256 tile. h5 = xcatH(16384x512) * B5(512x1024) ----------------
__global__ __launch_bounds__(256) void k_conv5_mfma(
    const _Float16* __restrict__ xh, const _Float16* __restrict__ Bp,
    const float* __restrict__ gamma,
    _Float16* __restrict__ h5, float* __restrict__ part) {
  __shared__ __align__(16) _Float16 ldsA[64 * 64];
  __shared__ __align__(16) _Float16 ldsB[32 * 512];
  __shared__ float ldsS[2][256], ldsQ[2][256], ldsMx[2][256], ldsMn[2][256];
  int tid = threadIdx.x, wv = tid >> 6, l = tid & 63;
  int mblk = blockIdx.x & 255, nid = blockIdx.x >> 8;
  int m0 = mblk * 64;
  int n_base = nid * 256;
  int mg = wv & 1, ng = wv >> 1;
  f32x4 acc[2][8];
#pragma unroll
  for (int m = 0; m < 2; ++m)
#pragma unroll
    for (int s = 0; s < 8; ++s)
#pragma unroll
      for (int r = 0; r < 4; ++r) acc[m][s][r] = 0.f;

  for (int ch = 0; ch < 8; ++ch) {
#pragma unroll
    for (int it = 0; it < 2; ++it) {
      int r0 = wv * 16 + it * 8;
      int R = r0 + (l >> 3);
      int q = (l & 7) ^ (l >> 3);
      gload_lds16(xh + (size_t)(m0 + R) * 512 + ch * 64 + q * 8, ldsA + r0 * 64);
    }
    for (int u = wv; u < 32; u += 4) {
      int ks = u >> 4, sloc = u & 15;
      gload_lds16(Bp + ((size_t)((ch * 2 + ks) * 64 + (n_base >> 4) + sloc) * 64 + l) * 8,
                  ldsB + u * 512);
    }
    __syncthreads();
#pragma unroll
    for (int ks = 0; ks < 2; ++ks) {
      half8 b[8];
#pragma unroll
      for (int s = 0; s < 8; ++s)
        b[s] = *(const half8*)(ldsB + (ks * 16 + ng * 8 + s) * 512 + l * 8);
#pragma unroll
      for (int mt = 0; mt < 2; ++mt) {
        int row = mg * 32 + mt * 16 + (l & 15);
        int slot = (ks * 4 + (l >> 4)) ^ (row & 7);
        half8 a = *(const half8*)(ldsA + row * 64 + slot * 8);
#pragma unroll
        for (int s = 0; s < 8; ++s)
          acc[mt][s] = __builtin_amdgcn_mfma_f32_16x16x32_f16(a, b[s], acc[mt][s], 0, 0, 0);
      }
    }
    __syncthreads();
  }
  int g = l >> 4;
#pragma unroll
  for (int s = 0; s < 8; ++s) {
    float sm = 0.f, sq = 0.f, mx = -3.4e38f, mn = 3.4e38f;
    int col = n_base + ng * 128 + s * 16 + (l & 15);
#pragma unroll
    for (int mt = 0; mt < 2; ++mt)
#pragma unroll
      for (int r = 0; r < 4; ++r) {
        float v = acc[mt][s][r];
        int row = m0 + mg * 32 + mt * 16 + 4 * g + r;
        h5[(size_t)row * 1024 + col] = (_Float16)v;
        sm += v; sq += v * v; mx = fmaxf(mx, v); mn = fminf(mn, v);
      }
    sm += __shfl_xor(sm, 16); sm += __shfl_xor(sm, 32);
    sq += __shfl_xor(sq, 16); sq += __shfl_xor(sq, 32);
    mx = fmaxf(mx, __shfl_xor(mx, 16)); mx = fmaxf(mx, __shfl_xor(mx, 32));
    mn = fminf(mn, __shfl_xor(mn, 16)); mn = fminf(mn, __shfl_xor(mn, 32));
    if (l < 16) {
      int u = ng * 128 + s * 16 + l;
      ldsS[mg][u] = sm; ldsQ[mg][u] = sq; ldsMx[mg][u] = mx; ldsMn[mg][u] = mn;
    }
  }
  __syncthreads();
  {
    int u = tid;
    int col = n_base + u;
    part[(size_t)mblk * 1024 + col] = ldsS[0][u] + ldsS[1][u];
    part[((size_t)256 + mblk) * 1024 + col] = ldsQ[0][u] + ldsQ[1][u];
    float sel = (gamma[col] >= 0.f) ? fmaxf(ldsMx[0][u], ldsMx[1][u])
                                    : fminf(ldsMn[0][u], ldsMn[1][u]);
    part[((size_t)512 + mblk) * 1024 + col] = sel;
  }
}

// reduce partials -> per-channel BN scale/shift. grid = O blocks.
__global__ __launch_bounds__(256) void k_finalize(
    const float* __restrict__ part, int G, int O, float inv_count,
    const float* __restrict__ gamma, const float* __restrict__ beta,
    float* __restrict__ ss) {
  int o = blockIdx.x;
  float s = 0.f, s2 = 0.f;
  for (int g = threadIdx.x; g < G; g += 256) {
    s  += part[(size_t)g * O + o];
    s2 += part[((size_t)G + g) * O + o];
  }
#pragma unroll
  for (int sft = 32; sft; sft >>= 1) {
    s  += __shfl_down(s, sft);
    s2 += __shfl_down(s2, sft);
  }
  __shared__ float aw[4], aw2[4];
  int w = threadIdx.x >> 6;
  if ((threadIdx.x & 63) == 0) { aw[w] = s; aw2[w] = s2; }
  __syncthreads();
  if (threadIdx.x == 0) {
    s = aw[0] + aw[1] + aw[2] + aw[3];
    s2 = aw2[0] + aw2[1] + aw2[2] + aw2[3];
    float m   = s * inv_count;
    float var = s2 * inv_count - m * m;
    float scale = gamma[o] * rsqrtf(var + 1e-5f);
    ss[o]     = scale;
    ss[O + o] = beta[o] - m * scale;
  }
}

// apply BN+lrelu to the sign-selected extremum; write fp16 into xcatH slice.
__global__ void k_edge_apply(const float* __restrict__ hsel,
                             const float* __restrict__ ss, _Float16* __restrict__ xh,
                             int O, int off) {
  int t = blockIdx.x * 256 + threadIdx.x;   // over BN*O/4
  int cgn = O >> 2;
  int gq = t % cgn;
  int p = t / cgn;
  int o = gq * 4;
  float4 sc = *(const float4*)&ss[o];
  float4 sh = *(const float4*)&ss[O + o];
  float4 v = *(const float4*)&hsel[(size_t)p * O + o];
  float y0 = sc.x * v.x + sh.x; y0 = (y0 >= 0.f) ? y0 : 0.2f * y0;
  float y1 = sc.y * v.y + sh.y; y1 = (y1 >= 0.f) ? y1 : 0.2f * y1;
  float y2 = sc.z * v.z + sh.z; y2 = (y2 >= 0.f) ? y2 : 0.2f * y2;
  float y3 = sc.w * v.w + sh.w; y3 = (y3 >= 0.f) ? y3 : 0.2f * y3;
  half4v out;
  out[0] = (_Float16)y0; out[1] = (_Float16)y1;
  out[2] = (_Float16)y2; out[3] = (_Float16)y3;
  *(half4v*)&xh[(size_t)p * 512 + off + o] = out;
}

// conv5 mean-pool partials: grid = 8b*8ns*4cg = 256 blocks
__global__ __launch_bounds__(256) void k_pool5a(const _Float16* __restrict__ h5,
                                                const float* __restrict__ ss,
                                                float* __restrict__ pmean) {
  int bi = blockIdx.x;
  int b = bi >> 5, ns = (bi >> 2) & 7, cg = bi & 3;
  int col = cg * 256 + threadIdx.x;
  float scale = ss[col], shift = ss[1024 + col];
  float sm = 0.f;
  for (int n = ns * 256; n < ns * 256 + 256; ++n) {
    float v = (float)h5[(size_t)(b * 2048 + n) * 1024 + col];
    float y = scale * v + shift;
    y = (y >= 0.f) ? y : 0.2f * y;
    sm += y;
  }
  pmean[(size_t)(b * 8 + ns) * 1024 + col] = sm;
}

// final pool: exact extremum via fp32 sign-selected partials, mean via pmean
__global__ __launch_bounds__(256) void k_pool5b(const float* __restrict__ part,
                                                const float* __restrict__ pmean,
                                                const float* __restrict__ ss,
                                                float* __restrict__ z) {
  int bi = blockIdx.x;
  int b = bi >> 2, cg = bi & 3;
  int col = cg * 256 + threadIdx.x;
  float scale = ss[col], shift = ss[1024 + col];
  const float* psel = part + (size_t)512 * 1024;
  bool pos = scale >= 0.f;
  float hv = pos ? -3.4e38f : 3.4e38f;
  for (int q = 0; q < 32; ++q) {
    float v = psel[(size_t)(b * 32 + q) * 1024 + col];
    hv = pos ? fmaxf(hv, v) : fminf(hv, v);
  }
  float zmax = scale * hv + shift;
  zmax = (zmax >= 0.f) ? zmax : 0.2f * zmax;
  float sm = 0.f;
  for (int ns = 0; ns < 8; ++ns) sm += pmean[(size_t)(b * 8 + ns) * 1024 + col];
  z[b * 2048 + col] = zmax;
  z[b * 2048 + 1024 + col] = sm * (1.f / 2048.f);
}

// FC L1: one wave per (b,o); fp16 weights (half8 = 16B/lane)
__global__ __launch_bounds__(64) void k_fc(const float* __restrict__ in,
                                           const _Float16* __restrict__ Wf,
                                           float* __restrict__ out, int IN, int O) {
  int blk = blockIdx.x;
  int b = blk / O, o = blk % O;
  const float4* a = (const float4*)(in + (size_t)b * IN);
  const half8* w = (const half8*)(Wf + (size_t)o * IN);
  float s = 0.f;
  for (int i = threadIdx.x; i < (IN >> 3); i += 64) {
    half8 wv = w[i];
    float4 a0 = a[2 * i], a1 = a[2 * i + 1];
    s += a0.x * (float)wv[0] + a0.y * (float)wv[1] + a0.z * (float)wv[2] + a0.w * (float)wv[3]
       + a1.x * (float)wv[4] + a1.y * (float)wv[5] + a1.z * (float)wv[6] + a1.w * (float)wv[7];
  }
#pragma unroll
  for (int sft = 32; sft; sft >>= 1) s += __shfl_down(s, sft);
  if (threadIdx.x == 0) out[(size_t)b * O + o] = s;
}

// fc2 with fused bn6: each block re-derives the tiny batch-BN (8x512) in LDS,
// then 4 waves compute 4 (b,o) dot products. grid = NB*256/4 = 512 blocks.
__global__ __launch_bounds__(256) void k_fc2bn(
    const float* __restrict__ z1p,
    const float* __restrict__ g6, const float* __restrict__ bt6,
    const float* __restrict__ L2, const float* __restrict__ bl2,
    float* __restrict__ z2p) {
  __shared__ float z1[NB * 512];
  int tid = threadIdx.x;
  for (int u = tid; u < NB * 512; u += 256) z1[u] = z1p[u];
  __syncthreads();
#pragma unroll
  for (int cc = 0; cc < 2; ++cc) {       // each thread owns 2 channels exclusively
    int c = tid + cc * 256;
    float s = 0.f, s2 = 0.f;
#pragma unroll
    for (int b = 0; b < NB; ++b) {
      float v = z1[b * 512 + c];
      s += v; s2 += v * v;
    }
    float m = s * (1.f / NB);
    float var = s2 * (1.f / NB) - m * m;
    float scale = g6[c] * rsqrtf(var + 1e-5f);
    float shift = bt6[c] - m * scale;
#pragma unroll
    for (int b = 0; b < NB; ++b) {
      float y = scale * z1[b * 512 + c] + shift;
      z1[b * 512 + c] = (y >= 0.f) ? y : 0.2f * y;
    }
  }
  __syncthreads();
  int wv = tid >> 6, l = tid & 63;
  int u = blockIdx.x * 4 + wv;           // output index over NB*256
  int b = u >> 8, o = u & 255;
  const float4* a = (const float4*)&z1[b * 512];
  const float4* w = (const float4*)(L2 + (size_t)o * 512);
  float s = 0.f;
#pragma unroll
  for (int i = l; i < 128; i += 64) {
    float4 av = a[i], wvv = w[i];
    s += av.x * wvv.x + av.y * wvv.y + av.z * wvv.z + av.w * wvv.w;
  }
#pragma unroll
  for (int sft = 32; sft; sft >>= 1) s += __shfl_down(s, sft);
  if (l == 0) z2p[u] = s + bl2[o];
}

// fc3 with fused bn7: grid = NB*40/4 = 80 blocks.
__global__ __launch_bounds__(256) void k_fc3bn(
    const float* __restrict__ z2p,
    const float* __restrict__ g7, const float* __restrict__ bt7,
    const float* __restrict__ L3, const float* __restrict__ bl3,
    float* __restrict__ out) {
  __shared__ float z2[NB * 256];
  int tid = threadIdx.x;
  for (int u = tid; u < NB * 256; u += 256) z2[u] = z2p[u];
  __syncthreads();
  {
    int c = tid;                         // one channel per thread, exclusive
    float s = 0.f, s2 = 0.f;
#pragma unroll
    for (int b = 0; b < NB; ++b) {
      float v = z2[b * 256 + c];
      s += v; s2 += v * v;
    }
    float m = s * (1.f / NB);
    float var = s2 * (1.f / NB) - m * m;
    float scale = g7[c] * rsqrtf(var + 1e-5f);
    float shift = bt7[c] - m * scale;
#pragma unroll
    for (int b = 0; b < NB; ++b) {
      float y = scale * z2[b * 256 + c] + shift;
      z2[b * 256 + c] = (y >= 0.f) ? y : 0.2f * y;
    }
  }
  __syncthreads();
  int wv = tid >> 6, l = tid & 63;
  int u = blockIdx.x * 4 + wv;           // output index over NB*40
  int b = u / 40, o = u - b * 40;
  const float4* a = (const float4*)&z2[b * 256];
  const float4* w = (const float4*)(L3 + (size_t)o * 256);
  float s = 0.f;
  {
    float4 av = a[l], wvv = w[l];        // 64 float4 = 256 elems, one per lane
    s += av.x * wvv.x + av.y * wvv.y + av.z * wvv.z + av.w * wvv.w;
  }
#pragma unroll
  for (int sft = 32; sft; sft >>= 1) s += __shfl_down(s, sft);
  if (l == 0) out[u] = s + bl3[o];
}

// ---------------- launcher ----------------
extern "C" void kernel_launch(void* const* d_in, const int* in_sizes, int n_in,
                              void* d_out, int out_size, void* d_ws, size_t ws_size,
                              hipStream_t stream) {
  (void)in_sizes; (void)n_in; (void)out_size; (void)ws_size;
  const float* x    = (const float*)d_in[0];
  const float* geod = (const float*)d_in[1];
  const float* W1   = (const float*)d_in[2];
  const float* g1   = (const float*)d_in[3];
  const float* bt1  = (const float*)d_in[4];
  const float* W2   = (const float*)d_in[5];
  const float* g2   = (const float*)d_in[6];
  const float* bt2  = (const float*)d_in[7];
  const float* W3   = (const float*)d_in[8];
  const float* g3   = (const float*)d_in[9];
  const float* bt3  = (const float*)d_in[10];
  const float* W4   = (const float*)d_in[11];
  const float* g4   = (const float*)d_in[12];
  const float* bt4  = (const float*)d_in[13];
  const float* W5   = (const float*)d_in[14];
  const float* g5   = (const float*)d_in[15];
  const float* bt5  = (const float*)d_in[16];
  const float* L1   = (const float*)d_in[17];
  const float* g6   = (const float*)d_in[18];
  const float* bt6  = (const float*)d_in[19];
  const float* L2   = (const float*)d_in[20];
  const float* bl2  = (const float*)d_in[21];
  const float* g7   = (const float*)d_in[22];
  const float* bt7  = (const float*)d_in[23];
  const float* L3   = (const float*)d_in[24];
  const float* bl3  = (const float*)d_in[25];

  char* ws = (char*)d_ws;
  int*       idx   = (int*)(ws + OFF_IDX);
  float*     xt    = (float*)(ws + OFF_XT);
  _Float16*  xcatH = (_Float16*)(ws + OFF_XCATH);
  float*     wt1   = (float*)(ws + OFF_WT1);
  float*     wd1   = (float*)(ws + OFF_WD1);
  _Float16*  bc2   = (_Float16*)(ws + OFF_BC2);
  _Float16*  bc3   = (_Float16*)(ws + OFF_BC3);
  _Float16*  bc4   = (_Float16*)(ws + OFF_BC4);
  _Float16*  b5    = (_Float16*)(ws + OFF_B5);
  _Float16*  yH    = (_Float16*)(ws + OFF_YH);
  float*     hsel  = (float*)(ws + OFF_HSEL);
  _Float16*  h5    = (_Float16*)(ws + OFF_H5);
  float*     part  = (float*)(ws + OFF_PART);
  float*     pmean = (float*)(ws + OFF_PMEAN);
  float*     ssb   = (float*)(ws + OFF_SS);
  float*     z     = (float*)(ws + OFF_Z);
  float*     z1p   = (float*)(ws + OFF_Z1P);
  float*     z2p   = (float*)(ws + OFF_Z2P);
  _Float16*  l1h   = (_Float16*)(ws + OFF_L1H);

  const float invE = 1.f / (float)(BN * NK);
  const float inv5 = 1.f / (float)(BN);

  // fused topk (first) + prep (independent work in one dispatch)
  k_prep_topk<<<NTOPK + PB_END, 256, 0, stream>>>(x, xt, W1, wt1, wd1,
                                                  W2, bc2, W3, bc3, W4, bc4, W5, b5,
                                                  L1, l1h, geod, idx);

  // layer 1 (C=3, fp32, whole-cloud LDS)
  k_edge1<<<512, 256, 0, stream>>>(xt, idx, wt1, wd1, g1, hsel, part);
  k_finalize<<<64, 256, 0, stream>>>(part, 512, 64, invE, g1, bt1, ssb);
  k_edge_apply<<<(BN * 64) / 1024, 256, 0, stream>>>(hsel, ssb, xcatH, 64, 0);
  // layer 2 (C=64 -> O=64): dense y|sbase GEMM + gather
  k_dense_mfma<64, 128, 1><<<256, 256, 0, stream>>>(xcatH, 0, bc2, yH);
  k_gather<64><<<BN / 16, 256, 0, stream>>>(yH, idx, g2, hsel, part);
  k_finalize<<<64, 256, 0, stream>>>(part, BN / 16, 64, invE, g2, bt2, ssb);
  k_edge_apply<<<(BN * 64) / 1024, 256, 0, stream>>>(hsel, ssb, xcatH, 64, 64);
  // layer 3 (C=64 -> O=128)
  k_dense_mfma<64, 256, 1><<<256, 256, 0, stream>>>(xcatH, 64, bc3, yH);
  k_gather<128><<<BN / 8, 256, 0, stream>>>(yH, idx, g3, hsel, part);
  k_finalize<<<128, 256, 0, stream>>>(part, BN / 8, 128, invE, g3, bt3, ssb);
  k_edge_apply<<<(BN * 128) / 1024, 256, 0, stream>>>(hsel, ssb, xcatH, 128, 128);
  // layer 4 (C=128 -> O=256)
  k_dense_mfma<128, 512, 2><<<512, 256, 0, stream>>>(xcatH, 128, bc4, yH);
  k_gather<256><<<BN / 4, 256, 0, stream>>>(yH, idx, g4, hsel, part);
  k_finalize<<<256, 256, 0, stream>>>(part, BN / 4, 256, invE, g4, bt4, ssb);
  k_edge_apply<<<(BN * 256) / 1024, 256, 0, stream>>>(hsel, ssb, xcatH, 256, 256);

  // conv5 (16384x512 @ 512x1024), 64x256 tile (3 blocks/CU — proven config)
  k_conv5_mfma<<<1024, 256, 0, stream>>>(xcatH, b5, g5, h5, part);
  k_finalize<<<1024, 256, 0, stream>>>(part, 256, 1024, inv5, g5, bt5, ssb);
  k_pool5a<<<256, 256, 0, stream>>>(h5, ssb, pmean);
  k_pool5b<<<32, 256, 0, stream>>>(part, pmean, ssb, z);

  // FC head (multi-block; batch-BNs fused into the GEMM kernels)
  k_fc<<<NB * 512, 64, 0, stream>>>(z, l1h, z1p, 2048, 512);
  k_fc2bn<<<NB * 256 / 4, 256, 0, stream>>>(z1p, g6, bt6, L2, bl2, z2p);
  k_fc3bn<<<NB * 40 / 4, 256, 0, stream>>>(z2p, g7, bt7, L3, bl3, (float*)d_out);
}